// Round 2
// baseline (133.505 us; speedup 1.0000x reference)
//
#include <hip/hip_runtime.h>
#include <hip/hip_bf16.h>
#include <string.h>

// Problem constants
#define NB    4096      // batch rows
#define IND_  512       // feature dim
#define OUTD_ 512       // output dim (GEMM M, "o")
#define XCOLS 514       // P + IND
#define ND    25        // D^P
#define KTOT  12800     // IND_*ND
#define KT2B  12928     // KTOT + 128-col bias tail (fp8 bytes per Wf8 row)
#define NSPL  4         // split-K (R15-proven)

// GEMM tiling (v4: 256x128 tile, 8 waves, depth-3 counted-vmcnt pipeline)
#define BM 256          // o rows per block
#define BN 128          // b rows per block
#define BKB 128         // K-window per iter (fp8 bytes == elements)

// prep_w tiling (R18-proven v2)
#define PWI 64
#define PWO 4
#define PWC (PWO * ND)   // 100 columns (o_l*25 + d)
#define T8P 112          // tile8 padded byte stride

typedef float  f32x4  __attribute__((ext_vector_type(4)));
typedef int    i32x4  __attribute__((ext_vector_type(4)));
typedef int    i32x8  __attribute__((ext_vector_type(8)));
typedef unsigned short u16x4 __attribute__((ext_vector_type(4)));
typedef unsigned int   u32x2 __attribute__((ext_vector_type(2)));

__device__ __forceinline__ unsigned short f2bf(float f) {
  unsigned int x = __float_as_uint(f);
  return (unsigned short)((x + 0x7fffu + ((x >> 16) & 1u)) >> 16);
}

__device__ __forceinline__ float bf2f(unsigned short u) {
  return __uint_as_float(((unsigned int)u) << 16);
}

__device__ __forceinline__ unsigned int pk_bf16(float a, float b) {
  return (unsigned int)f2bf(a) | ((unsigned int)f2bf(b) << 16);
}

// Software fp32 -> OCP e4m3fn, RNE, for v >= 0 (all values < 1.2).
__device__ __forceinline__ unsigned char f2fp8(float v) {
  if (v < 0.015625f) {
    return (unsigned char)__float2int_rn(v * 512.0f);
  }
  unsigned int u = __float_as_uint(v);
  u += 0x7ffffu + ((u >> 20) & 1u);
  int e = (int)(u >> 23) - 127 + 7;
  unsigned int m = (u >> 20) & 7u;
  return (unsigned char)((e << 3) | m);
}

__device__ __forceinline__ float basis_f(float t, int j) {
  switch (j) {
    case 0: return 1.0f;
    case 1: return t;
    case 2: return t * t;
    case 3: { float r = t - 0.33f; r = r > 0.0f ? r : 0.0f; return r * r; }
    default:{ float r = t - 0.66f; r = r > 0.0f ? r : 0.0f; return r * r; }
  }
}

__device__ __forceinline__ void gload_lds16(const void* g, void* l) {
  __builtin_amdgcn_global_load_lds(
      (const __attribute__((address_space(1))) void*)g,
      (__attribute__((address_space(3))) void*)l, 16, 0, 0);
}

// ---------------------------------------------------------------------------
// prep_all v2 (R18-proven, unchanged): 1536 blocks.
//   [0,512):    prep_x — 8 rows/block: Xf8, kb fp32, kbT8, out[0:2]
//   [512,1536): prep_w — balanced f2fp8 in load stage, byte-gather store;
//               i0==0 blocks also write bias K-tail.
// Lessons: R9/R16 — cross-block handoff = kernel boundary (grid.sync ~55us,
// fence storm ~3ms); R12 — no LDS unions.
// ---------------------------------------------------------------------------
__global__ __launch_bounds__(256) void prep_all_kernel(
    const float* __restrict__ x, const float* __restrict__ W,
    const float* __restrict__ bias, unsigned char* __restrict__ Xf8,
    float* __restrict__ kb, unsigned char* __restrict__ kbT8,
    unsigned char* __restrict__ Wf8, float* __restrict__ out)
{
  __shared__ unsigned char tile8[PWI * T8P];   // 7 KB
  const int bid = blockIdx.x;
  const int tid = threadIdx.x;

  if (bid < 512) {
    const int lane = tid & 63;
    #pragma unroll
    for (int rr = 0; rr < 2; ++rr) {
      const int b = bid * 8 + (tid >> 6) * 2 + rr;
      const float* xr = x + (size_t)b * XCOLS;
      const float* fp = xr + 2 + lane * 8;
      float2 a0 = *(const float2*)(fp + 0);
      float2 a1 = *(const float2*)(fp + 2);
      float2 a2 = *(const float2*)(fp + 4);
      float2 a3 = *(const float2*)(fp + 6);
      float xf[8] = {a0.x, a0.y, a1.x, a1.y, a2.x, a2.y, a3.x, a3.y};
      u32x2 pk;
      pk[0] = (unsigned int)f2fp8(xf[0]) | ((unsigned int)f2fp8(xf[1]) << 8) |
              ((unsigned int)f2fp8(xf[2]) << 16) | ((unsigned int)f2fp8(xf[3]) << 24);
      pk[1] = (unsigned int)f2fp8(xf[4]) | ((unsigned int)f2fp8(xf[5]) << 8) |
              ((unsigned int)f2fp8(xf[6]) << 16) | ((unsigned int)f2fp8(xf[7]) << 24);
      *reinterpret_cast<u32x2*>(Xf8 + (size_t)b * IND_ + lane * 8) = pk;

      float t0 = xr[0], t1 = xr[1];
      if (lane < 2) out[(size_t)b * XCOLS + lane] = (lane == 0) ? t0 : t1;
      {
        int d1 = lane / 5, d2 = lane - d1 * 5;
        float kv = basis_f(t0, d1) * basis_f(t1, d2);
        if (lane < ND) kb[(size_t)b * ND + lane] = kv;
      }
      {
        int ta = 2 * lane, tb = 2 * lane + 1;
        unsigned char ba = 0, bb = 0;
        if (ta < ND) { int d1 = ta / 5, d2 = ta - d1 * 5;
                       ba = f2fp8(basis_f(t0, d1) * basis_f(t1, d2)); }
        if (tb < ND) { int d1 = tb / 5, d2 = tb - d1 * 5;
                       bb = f2fp8(basis_f(t0, d1) * basis_f(t1, d2)); }
        *(unsigned short*)(kbT8 + (size_t)b * 128 + 2 * lane) =
            (unsigned short)ba | ((unsigned short)bb << 8);
      }
    }
  } else {
    const int pw = bid - 512;
    const int i0 = (pw & 7) * PWI;
    const int o0 = (pw >> 3) * PWO;

    for (int t = tid; t < PWI * (PWC / 4); t += 256) {
      int il = t / (PWC / 4);
      int c4 = t - il * (PWC / 4);
      float4 v = *(const float4*)(W + ((size_t)(i0 + il) * OUTD_ + o0) * ND + c4 * 4);
      unsigned int pk = (unsigned int)f2fp8(v.x) | ((unsigned int)f2fp8(v.y) << 8) |
                        ((unsigned int)f2fp8(v.z) << 16) | ((unsigned int)f2fp8(v.w) << 24);
      *(unsigned int*)&tile8[il * T8P + c4 * 4] = pk;
    }
    __syncthreads();

    for (int g = tid; g < PWC * (PWI / 8); g += 256) {
      int c  = g >> 3;
      int ig = g & 7;
      int d  = c % 25;
      int o_l = c / 25;
      unsigned long long v = 0;
      #pragma unroll
      for (int jj = 0; jj < 8; ++jj)
        v |= (unsigned long long)tile8[(ig * 8 + jj) * T8P + c] << (8 * jj);
      size_t rowb = (size_t)(o0 + o_l) * KT2B + (size_t)d * IND_ + i0;
      *reinterpret_cast<unsigned long long*>(Wf8 + rowb + ig * 8) = v;
    }

    if ((pw & 7) == 0) {
      int o = o0 + (tid >> 6);
      int p = tid & 63;
      int ta = 2 * p, tb = 2 * p + 1;
      unsigned char ba = (ta < ND) ? f2fp8(bias[o * ND + ta]) : (unsigned char)0;
      unsigned char bb = (tb < ND) ? f2fp8(bias[o * ND + tb]) : (unsigned char)0;
      *(unsigned short*)(Wf8 + (size_t)o * KT2B + KTOT + 2 * p) =
          (unsigned short)ba | ((unsigned short)bb << 8);
    }
  }
}

// ---------------------------------------------------------------------------
// gemm_mx v4: depth-3 triple-buffered pipeline with COUNTED vmcnt (T4).
// R19 post-mortem: per-iter time was 4368 cyc in BOTH the 128x128 (2 blk/CU)
// and 256x128 (1 blk/CU) geometries — invariant under staging volume, VALU
// work and occupancy.  MFMA floor is 1104 cyc/iter; the other ~3200 cyc was
// every wave parked at [s_waitcnt vmcnt(0); barrier] waiting for the DMA
// issued at the top of the SAME iteration (the m233-measured structural
// stall of the 2-phase schedule).  Fix per m218 (counted-vs-drain0
// = +38..73%): issue tile n+2 at iter n, and before each barrier wait only
// vmcnt(6) — tile n+1's 6 loads retired, tile n+2's 6 still IN FLIGHT
// across the barrier.  Each wave issues exactly 6 DMAs/iter, so the count
// is exact per wave (R7/R8 cross-wave discipline, counted form).  Raw
// s_barrier (HIP __syncthreads would re-insert the vmcnt(0) drain).
// WAR-safe: tile n+2 overwrites buf (n+2)%3 == (n-1)%3, whose ds_reads
// completed before iter n-1's barrier (MFMAs consumed them pre-barrier).
// Last two iters wait vmcnt(0) (nothing left to overlap; 2/25 iters).
// Bias K-tail folded back into the main loop as iter 25 (bz==3 only).
// T5 setprio(1) wraps the compute phase (pays in non-lockstep schedules).
// LDS 3x(32+16) = 144 KB -> 1 block/CU, 8 waves.
// ---------------------------------------------------------------------------
__global__ __launch_bounds__(512, 2) void gemm_mx_kernel(
    const unsigned char* __restrict__ Wf8, const unsigned char* __restrict__ Xf8,
    const float* __restrict__ kb, const unsigned char* __restrict__ kbT8,
    unsigned short* __restrict__ Pb)
{
  __shared__ unsigned char Als[3][BM * BKB];   // 3 x 32 KB
  __shared__ unsigned char Bls[3][BN * BKB];   // 3 x 16 KB

  const int tid  = threadIdx.x;
  const int lane = tid & 63;
  const int w    = tid >> 6;            // [0,8)
  const int l15  = lane & 15;
  const int quad = lane >> 4;

  const int id  = blockIdx.x;           // [0,256)
  const int xcd = id & 7;
  const int bx  = xcd & 1;              // o-tile [0,2)
  const int bz  = xcd >> 1;             // split  [0,4)
  const int by  = id >> 3;              // b-tile [0,32)

  const int o0 = bx * BM;
  const int b0 = by * BN;
  const int ks_begin = bz * 3200;       // 25 iters x 128
  const bool tail = (bz == 3);          // also does the 128-B bias K-tail
  const int nIter = tail ? 26 : 25;     // iter 25 == bias tail

  const int o_off = (w & 3) * 64;
  const int b_off = (w >> 2) * 64;
  const int srow  = lane >> 3;
  const int scol  = ((lane & 7) ^ srow) * 16;
  const int r7    = l15 & 7;
  const int s0    = ((2 * quad) ^ r7) * 16;
  const int s1    = ((2 * quad + 1) ^ r7) * 16;

  // Per-thread staging source bases (k advances as a wave-uniform scalar).
  // A: 32 chunks of 8 rows (1 KB each), wave w stages chunks w*4..w*4+3.
  // B: 16 chunks, wave w stages chunks w*2..w*2+1.
  const unsigned char* aRow[4];
  #pragma unroll
  for (int c = 0; c < 4; ++c)
    aRow[c] = Wf8 + (size_t)(o0 + (w * 4 + c) * 8 + srow) * KT2B + scol;
  const unsigned char* bRow[2];
  #pragma unroll
  for (int c = 0; c < 2; ++c)
    bRow[c] = Xf8 + (size_t)(b0 + (w * 2 + c) * 8 + srow) * IND_ + scol;
  const unsigned char* tRow[2];
  #pragma unroll
  for (int c = 0; c < 2; ++c)
    tRow[c] = kbT8 + (size_t)(b0 + (w * 2 + c) * 8 + srow) * 128 + scol;

  f32x4 acc[4][4], fin[4][4];
  #pragma unroll
  for (int i = 0; i < 4; ++i)
    #pragma unroll
    for (int jj = 0; jj < 4; ++jj) { acc[i][jj] = (f32x4)0.0f; fin[i][jj] = (f32x4)0.0f; }

  float kv[4] = {1.0f, 1.0f, 1.0f, 1.0f};
  int cur_d = -1;

  // stage tile m (m==25 -> bias tail) into buf
  auto issue_for = [&](int m, int buf) {
    if (m < 25) {
      const int ao   = ks_begin + m * BKB;
      const int bcol = ao & 511;
      #pragma unroll
      for (int c = 0; c < 4; ++c)
        gload_lds16(aRow[c] + ao, &Als[buf][(w * 4 + c) * 1024]);
      #pragma unroll
      for (int c = 0; c < 2; ++c)
        gload_lds16(bRow[c] + bcol, &Bls[buf][(w * 2 + c) * 1024]);
    } else {
      #pragma unroll
      for (int c = 0; c < 4; ++c)
        gload_lds16(aRow[c] + KTOT, &Als[buf][(w * 4 + c) * 1024]);
      #pragma unroll
      for (int c = 0; c < 2; ++c)
        gload_lds16(tRow[c], &Bls[buf][(w * 2 + c) * 1024]);
    }
  };

  // prologue: fill bufs 0 and 1 (12 loads in flight), wait for buf 0 only
  issue_for(0, 0);
  issue_for(1, 1);
  asm volatile("s_waitcnt vmcnt(6)" ::: "memory");
  __builtin_amdgcn_s_barrier();

  int p = 0;
  for (int n = 0; n < nIter; ++n) {
    int q = p + 2; if (q >= 3) q -= 3;
    const bool more2 = (n + 2 < nIter);
    if (more2) issue_for(n + 2, q);     // in flight across the next barrier

    const int d = (n < 25) ? ((ks_begin + n * BKB) >> 9) : ND;
    if (d != cur_d) {
      if (cur_d >= 0) {
        #pragma unroll
        for (int nf = 0; nf < 4; ++nf)
          #pragma unroll
          for (int mf = 0; mf < 4; ++mf)
            #pragma unroll
            for (int r = 0; r < 4; ++r) {
              fin[mf][nf][r] += kv[nf] * acc[mf][nf][r];
              acc[mf][nf][r] = 0.0f;
            }
      }
      cur_d = d;
      if (d < ND) {
        #pragma unroll
        for (int nf = 0; nf < 4; ++nf)
          kv[nf] = kb[(size_t)(b0 + b_off + nf * 16 + l15) * ND + d];
      } else {
        #pragma unroll
        for (int nf = 0; nf < 4; ++nf) kv[nf] = 1.0f;
      }
    }

    // compute phase: 16 scaled MFMAs on buf p
    __builtin_amdgcn_s_setprio(1);
    {
      i32x8 af[4], bfr[4];
      #pragma unroll
      for (int mf = 0; mf < 4; ++mf) {
        int rb = (o_off + mf * 16 + l15) * BKB;
        i32x4 lo = *reinterpret_cast<const i32x4*>(&Als[p][rb + s0]);
        i32x4 hi = *reinterpret_cast<const i32x4*>(&Als[p][rb + s1]);
        i32x8 v;
        v[0] = lo[0]; v[1] = lo[1]; v[2] = lo[2]; v[3] = lo[3];
        v[4] = hi[0]; v[5] = hi[1]; v[6] = hi[2]; v[7] = hi[3];
        af[mf] = v;
      }
      #pragma unroll
      for (int nf = 0; nf < 4; ++nf) {
        int rb = (b_off + nf * 16 + l15) * BKB;
        i32x4 lo = *reinterpret_cast<const i32x4*>(&Bls[p][rb + s0]);
        i32x4 hi = *reinterpret_cast<const i32x4*>(&Bls[p][rb + s1]);
        i32x8 v;
        v[0] = lo[0]; v[1] = lo[1]; v[2] = lo[2]; v[3] = lo[3];
        v[4] = hi[0]; v[5] = hi[1]; v[6] = hi[2]; v[7] = hi[3];
        bfr[nf] = v;
      }
      #pragma unroll
      for (int mf = 0; mf < 4; ++mf)
        #pragma unroll
        for (int nf = 0; nf < 4; ++nf)
          acc[mf][nf] = __builtin_amdgcn_mfma_scale_f32_16x16x128_f8f6f4(
              af[mf], bfr[nf], acc[mf][nf],
              0, 0, 0, 0x7f7f7f7f, 0, 0x7f7f7f7f);
    }
    __builtin_amdgcn_s_setprio(0);

    // counted wait: retire tile n+1's 6 loads; tile n+2's stay in flight.
    if (n + 1 < nIter) {
      if (more2) {
        asm volatile("s_waitcnt vmcnt(6)" ::: "memory");
      } else {
        asm volatile("s_waitcnt vmcnt(0)" ::: "memory");
      }
      __builtin_amdgcn_s_barrier();
    }
    p = (p + 1 == 3) ? 0 : p + 1;
  }

  // final flush (last d-group of this split; bz==3's tail group has kv==1)
  #pragma unroll
  for (int nf = 0; nf < 4; ++nf)
    #pragma unroll
    for (int mf = 0; mf < 4; ++mf)
      #pragma unroll
      for (int r = 0; r < 4; ++r)
        fin[mf][nf][r] += kv[nf] * acc[mf][nf][r];

  // store partial as bf16
  unsigned short* Pz = Pb + (size_t)bz * NB * OUTD_;
  #pragma unroll
  for (int mf = 0; mf < 4; ++mf)
    #pragma unroll
    for (int nf = 0; nf < 4; ++nf) {
      int bg = b0 + b_off + nf * 16 + l15;
      int og = o0 + o_off + mf * 16 + quad * 4;
      u32x2 pk;
      pk[0] = pk_bf16(fin[mf][nf][0], fin[mf][nf][1]);
      pk[1] = pk_bf16(fin[mf][nf][2], fin[mf][nf][3]);
      *reinterpret_cast<u32x2*>(&Pz[(size_t)bg * OUTD_ + og]) = pk;
    }
}

// ---------------------------------------------------------------------------
// epilogue: out[b][2+o..2+o+3] = relu(P0+P1+P2+P3)  (bias in K-tail)
// ---------------------------------------------------------------------------
__global__ __launch_bounds__(256) void epilogue_kernel(
    const unsigned short* __restrict__ Pb, float* __restrict__ out)
{
  const int idx = (blockIdx.x * 256 + threadIdx.x) * 4;   // < 4096*512
  const int b = idx >> 9;
  const int o = idx & 511;
  const size_t ps = (size_t)NB * OUTD_;
  float s[4] = {0.0f, 0.0f, 0.0f, 0.0f};
  #pragma unroll
  for (int z = 0; z < NSPL; ++z) {
    u16x4 v = *reinterpret_cast<const u16x4*>(&Pb[z * ps + idx]);
    #pragma unroll
    for (int e = 0; e < 4; ++e) s[e] += bf2f(v[e]);
  }
  float* op = out + (size_t)b * XCOLS + 2 + o;   // 8B-aligned
  float2 lo, hi;
  lo.x = s[0] > 0.0f ? s[0] : 0.0f;
  lo.y = s[1] > 0.0f ? s[1] : 0.0f;
  hi.x = s[2] > 0.0f ? s[2] : 0.0f;
  hi.y = s[3] > 0.0f ? s[3] : 0.0f;
  *(float2*)op = lo;
  *(float2*)(op + 2) = hi;
}

// ---------------------------------------------------------------------------
extern "C" void kernel_launch(void* const* d_in, const int* in_sizes, int n_in,
                              void* d_out, int out_size, void* d_ws, size_t ws_size,
                              hipStream_t stream) {
  const float* x    = (const float*)d_in[0];   // 4096 x 514
  const float* W    = (const float*)d_in[1];   // 512 x 512 x 25
  const float* bias = (const float*)d_in[2];   // 512 x 25
  float* out = (float*)d_out;
  char* ws = (char*)d_ws;

  // ws layout (bytes):
  //   Xf8 2,097,152 | Wf8 512*12928 = 6,619,136 | kb 409,600
  //   kbT8 524,288 | Pb 4*4096*512*2 = 16,777,216   (total ~26.4 MB)
  const size_t xf_off  = 0;
  const size_t wf_off  = 2097152;
  const size_t kb_off  = wf_off + (size_t)OUTD_ * KT2B;
  const size_t kbt_off = kb_off + 409600;
  const size_t p_off   = kbt_off + (size_t)NB * 128;
  unsigned char* Xf8  = (unsigned char*)(ws + xf_off);
  unsigned char* Wf8  = (unsigned char*)(ws + wf_off);
  float* kb           = (float*)(ws + kb_off);
  unsigned char* kbT8 = (unsigned char*)(ws + kbt_off);
  unsigned short* Pb  = (unsigned short*)(ws + p_off);

  prep_all_kernel<<<1536, 256, 0, stream>>>(x, W, bias, Xf8, kb, kbT8, Wf8, out);
  gemm_mx_kernel<<<256, 512, 0, stream>>>(Wf8, Xf8, kb, kbT8, Pb);
  epilogue_kernel<<<(NB * OUTD_) / 1024, 256, 0, stream>>>(Pb, out);
}

// Round 3
// 126.811 us; speedup vs baseline: 1.0528x; 1.0528x over previous
//
#include <hip/hip_runtime.h>
#include <hip/hip_bf16.h>
#include <string.h>

// Problem constants
#define NB    4096      // batch rows
#define IND_  512       // feature dim
#define OUTD_ 512       // output dim (GEMM M, "o")
#define XCOLS 514       // P + IND
#define ND    25        // D^P
#define KTOT  12800     // IND_*ND
#define KT2B  12928     // KTOT + 128-col bias tail (fp8 bytes per Wf8 row)
#define NSPL  4         // split over 4 i-windows (v5)

// GEMM tiling (v5: 256x128 tile, 8 waves, B-in-registers, d-inner loop)
#define BM 256          // o rows per block
#define BN 128          // b rows per block
#define BKB 128         // K-window per iter (fp8 bytes == elements)

// prep_w tiling (R18-proven v2)
#define PWI 64
#define PWO 4
#define PWC (PWO * ND)   // 100 columns (o_l*25 + d)
#define T8P 112          // tile8 padded byte stride

typedef float  f32x4  __attribute__((ext_vector_type(4)));
typedef int    i32x4  __attribute__((ext_vector_type(4)));
typedef int    i32x8  __attribute__((ext_vector_type(8)));
typedef unsigned short u16x4 __attribute__((ext_vector_type(4)));
typedef unsigned int   u32x2 __attribute__((ext_vector_type(2)));

__device__ __forceinline__ unsigned short f2bf(float f) {
  unsigned int x = __float_as_uint(f);
  return (unsigned short)((x + 0x7fffu + ((x >> 16) & 1u)) >> 16);
}

__device__ __forceinline__ float bf2f(unsigned short u) {
  return __uint_as_float(((unsigned int)u) << 16);
}

__device__ __forceinline__ unsigned int pk_bf16(float a, float b) {
  return (unsigned int)f2bf(a) | ((unsigned int)f2bf(b) << 16);
}

// Software fp32 -> OCP e4m3fn, RNE, for v >= 0 (all values < 1.2).
__device__ __forceinline__ unsigned char f2fp8(float v) {
  if (v < 0.015625f) {
    return (unsigned char)__float2int_rn(v * 512.0f);
  }
  unsigned int u = __float_as_uint(v);
  u += 0x7ffffu + ((u >> 20) & 1u);
  int e = (int)(u >> 23) - 127 + 7;
  unsigned int m = (u >> 20) & 7u;
  return (unsigned char)((e << 3) | m);
}

__device__ __forceinline__ float basis_f(float t, int j) {
  switch (j) {
    case 0: return 1.0f;
    case 1: return t;
    case 2: return t * t;
    case 3: { float r = t - 0.33f; r = r > 0.0f ? r : 0.0f; return r * r; }
    default:{ float r = t - 0.66f; r = r > 0.0f ? r : 0.0f; return r * r; }
  }
}

__device__ __forceinline__ void gload_lds16(const void* g, void* l) {
  __builtin_amdgcn_global_load_lds(
      (const __attribute__((address_space(1))) void*)g,
      (__attribute__((address_space(3))) void*)l, 16, 0, 0);
}

// ---------------------------------------------------------------------------
// prep_all v2 (R18-proven, unchanged): 1536 blocks.
// ---------------------------------------------------------------------------
__global__ __launch_bounds__(256) void prep_all_kernel(
    const float* __restrict__ x, const float* __restrict__ W,
    const float* __restrict__ bias, unsigned char* __restrict__ Xf8,
    float* __restrict__ kb, unsigned char* __restrict__ kbT8,
    unsigned char* __restrict__ Wf8, float* __restrict__ out)
{
  __shared__ unsigned char tile8[PWI * T8P];   // 7 KB
  const int bid = blockIdx.x;
  const int tid = threadIdx.x;

  if (bid < 512) {
    const int lane = tid & 63;
    #pragma unroll
    for (int rr = 0; rr < 2; ++rr) {
      const int b = bid * 8 + (tid >> 6) * 2 + rr;
      const float* xr = x + (size_t)b * XCOLS;
      const float* fp = xr + 2 + lane * 8;
      float2 a0 = *(const float2*)(fp + 0);
      float2 a1 = *(const float2*)(fp + 2);
      float2 a2 = *(const float2*)(fp + 4);
      float2 a3 = *(const float2*)(fp + 6);
      float xf[8] = {a0.x, a0.y, a1.x, a1.y, a2.x, a2.y, a3.x, a3.y};
      u32x2 pk;
      pk[0] = (unsigned int)f2fp8(xf[0]) | ((unsigned int)f2fp8(xf[1]) << 8) |
              ((unsigned int)f2fp8(xf[2]) << 16) | ((unsigned int)f2fp8(xf[3]) << 24);
      pk[1] = (unsigned int)f2fp8(xf[4]) | ((unsigned int)f2fp8(xf[5]) << 8) |
              ((unsigned int)f2fp8(xf[6]) << 16) | ((unsigned int)f2fp8(xf[7]) << 24);
      *reinterpret_cast<u32x2*>(Xf8 + (size_t)b * IND_ + lane * 8) = pk;

      float t0 = xr[0], t1 = xr[1];
      if (lane < 2) out[(size_t)b * XCOLS + lane] = (lane == 0) ? t0 : t1;
      {
        int d1 = lane / 5, d2 = lane - d1 * 5;
        float kv = basis_f(t0, d1) * basis_f(t1, d2);
        if (lane < ND) kb[(size_t)b * ND + lane] = kv;
      }
      {
        int ta = 2 * lane, tb = 2 * lane + 1;
        unsigned char ba = 0, bb = 0;
        if (ta < ND) { int d1 = ta / 5, d2 = ta - d1 * 5;
                       ba = f2fp8(basis_f(t0, d1) * basis_f(t1, d2)); }
        if (tb < ND) { int d1 = tb / 5, d2 = tb - d1 * 5;
                       bb = f2fp8(basis_f(t0, d1) * basis_f(t1, d2)); }
        *(unsigned short*)(kbT8 + (size_t)b * 128 + 2 * lane) =
            (unsigned short)ba | ((unsigned short)bb << 8);
      }
    }
  } else {
    const int pw = bid - 512;
    const int i0 = (pw & 7) * PWI;
    const int o0 = (pw >> 3) * PWO;

    for (int t = tid; t < PWI * (PWC / 4); t += 256) {
      int il = t / (PWC / 4);
      int c4 = t - il * (PWC / 4);
      float4 v = *(const float4*)(W + ((size_t)(i0 + il) * OUTD_ + o0) * ND + c4 * 4);
      unsigned int pk = (unsigned int)f2fp8(v.x) | ((unsigned int)f2fp8(v.y) << 8) |
                        ((unsigned int)f2fp8(v.z) << 16) | ((unsigned int)f2fp8(v.w) << 24);
      *(unsigned int*)&tile8[il * T8P + c4 * 4] = pk;
    }
    __syncthreads();

    for (int g = tid; g < PWC * (PWI / 8); g += 256) {
      int c  = g >> 3;
      int ig = g & 7;
      int d  = c % 25;
      int o_l = c / 25;
      unsigned long long v = 0;
      #pragma unroll
      for (int jj = 0; jj < 8; ++jj)
        v |= (unsigned long long)tile8[(ig * 8 + jj) * T8P + c] << (8 * jj);
      size_t rowb = (size_t)(o0 + o_l) * KT2B + (size_t)d * IND_ + i0;
      *reinterpret_cast<unsigned long long*>(Wf8 + rowb + ig * 8) = v;
    }

    if ((pw & 7) == 0) {
      int o = o0 + (tid >> 6);
      int p = tid & 63;
      int ta = 2 * p, tb = 2 * p + 1;
      unsigned char ba = (ta < ND) ? f2fp8(bias[o * ND + ta]) : (unsigned char)0;
      unsigned char bb = (tb < ND) ? f2fp8(bias[o * ND + tb]) : (unsigned char)0;
      *(unsigned short*)(Wf8 + (size_t)o * KT2B + KTOT + 2 * p) =
          (unsigned short)ba | ((unsigned short)bb << 8);
    }
  }
}

// ---------------------------------------------------------------------------
// gemm_mx v5: B-IN-REGISTERS, d-inner K-order, telescoping kv flush.
//
// R20 post-mortem model: per-iter time was pinned at ~4400 cyc across tile
// size / occupancy / pipeline depth / vmcnt discipline.  Pipe accounting:
// MFMA 1104 cyc/CU-iter (=MfmaUtil 20% ✓); LDS reads 128 x ds_read_b128
// x 12cyc = 1536 + 517 measured conflicts + 384 DMA-write = ~2450; VALU
// ~700.  Sum ≈ 4300 ≈ observed → the kernel was LDS-READ-SERVICE-BOUND
// with barrier-aligned phases (no read/MFMA cross-overlap).
//
// Structural fix: B (Xf8 columns) repeats every 4 K-iters (bcol = k&511).
// Reorder K: split-K = i-window (iw = which 128 X-cols), inner loop over
// d = 0..24.  B-tile is then CONSTANT -> staged once, held in bfr[4] regs
// (32 VGPR).  Per-iter LDS: 64 reads (A only) + 32 KB writes ≈ 1100 cyc
// < MFMA 1104 -> MFMA becomes the binding pipe.
// kv now changes every iter; use the TELESCOPING (Abel) flush: never reset
// acc, fin += (kv_d - kv_{d+1})*acc with kv_25 = 0 (algebraically exact:
// sum_d kv_d*A_d = sum_d (kv_d - kv_{d+1}) * sum_{m<=d} A_m).
// Bias tail (iw==3): kbT8 tile staged to BTls in the prologue; consumed
// after the main loop with MFMAs accumulating straight into fin (kv=1).
// Depth-3 counted-vmcnt A-pipeline kept (vmcnt FIFO: waiting vmcnt(8)
// retires everything except the 8 newest ops = A(n+2)x4 + kv-prefetch x4,
// so A(n+1) is guaranteed landed — exact under any load reordering since
// each iter boundary's asm memory clobber pins loads inside their iter).
// setprio DROPPED (R2: slight regression, = m190's lockstep-GEMM result).
// Grid 256 = (bx,iw) on XCD x 32 b-tiles: each XCD's 32 CUs stream the
// same 800 KB Wf8 panel (L2-resident).  LDS 3x32 + 16 + 16 = 128 KB.
// ---------------------------------------------------------------------------
__global__ __launch_bounds__(512, 2) void gemm_mx_kernel(
    const unsigned char* __restrict__ Wf8, const unsigned char* __restrict__ Xf8,
    const float* __restrict__ kb, const unsigned char* __restrict__ kbT8,
    unsigned short* __restrict__ Pb)
{
  __shared__ unsigned char Als[3][BM * BKB];   // 3 x 32 KB
  __shared__ unsigned char Bls[BN * BKB];      // 16 KB (X i-window, staged once)
  __shared__ unsigned char BTls[BN * BKB];     // 16 KB (kbT8 bias tail)

  const int tid  = threadIdx.x;
  const int lane = tid & 63;
  const int w    = tid >> 6;            // [0,8)
  const int l15  = lane & 15;
  const int quad = lane >> 4;

  const int id  = blockIdx.x;           // [0,256)
  const int bx  = id & 1;               // o-tile [0,2)
  const int iw  = (id >> 1) & 3;        // i-window (split) [0,4)
  const int by  = id >> 3;              // b-tile [0,32)

  const int o0 = bx * BM;
  const int b0 = by * BN;
  const bool tail = (iw == 3);          // also does the 128-B bias K-tail
  const int lastA = tail ? 25 : 24;     // last A-tile index (25 == bias block)

  const int o_off = (w & 3) * 64;
  const int b_off = (w >> 2) * 64;
  const int srow  = lane >> 3;
  const int scol  = ((lane & 7) ^ srow) * 16;
  const int r7    = l15 & 7;
  const int s0    = ((2 * quad) ^ r7) * 16;
  const int s1    = ((2 * quad + 1) ^ r7) * 16;

  // A staging: 32 chunks of 8 rows (1 KB); wave w stages chunks w*4..w*4+3.
  // A-tile m (m<25): byte offset m*512 + iw*128 in the Wf8 row; m==25: KTOT.
  const unsigned char* aRow[4];
  #pragma unroll
  for (int c = 0; c < 4; ++c)
    aRow[c] = Wf8 + (size_t)(o0 + (w * 4 + c) * 8 + srow) * KT2B + scol;

  auto issueA = [&](int m, int buf) {
    const int ko = (m < 25) ? (m * 512 + iw * 128) : KTOT;
    #pragma unroll
    for (int c = 0; c < 4; ++c)
      gload_lds16(aRow[c] + ko, &Als[buf][(w * 4 + c) * 1024]);
  };

  // ---- prologue: stage BT, B, A(0), A(1)  (12 DMAs per wave) ----
  #pragma unroll
  for (int c = 0; c < 2; ++c)
    gload_lds16(kbT8 + (size_t)(b0 + (w * 2 + c) * 8 + srow) * 128 + scol,
                &BTls[(w * 2 + c) * 1024]);
  #pragma unroll
  for (int c = 0; c < 2; ++c)
    gload_lds16(Xf8 + (size_t)(b0 + (w * 2 + c) * 8 + srow) * IND_ + iw * 128 + scol,
                &Bls[(w * 2 + c) * 1024]);
  issueA(0, 0);
  issueA(1, 1);
  // retire everything except the 4 newest (A(1)) -> BT, B, A(0) landed
  asm volatile("s_waitcnt vmcnt(4)" ::: "memory");
  __builtin_amdgcn_s_barrier();

  // ---- B fragments to registers (held for the whole kernel) ----
  i32x8 bfr[4];
  #pragma unroll
  for (int nf = 0; nf < 4; ++nf) {
    int rb = (b_off + nf * 16 + l15) * BKB;
    i32x4 lo = *reinterpret_cast<const i32x4*>(&Bls[rb + s0]);
    i32x4 hi = *reinterpret_cast<const i32x4*>(&Bls[rb + s1]);
    i32x8 v;
    v[0] = lo[0]; v[1] = lo[1]; v[2] = lo[2]; v[3] = lo[3];
    v[4] = hi[0]; v[5] = hi[1]; v[6] = hi[2]; v[7] = hi[3];
    bfr[nf] = v;
  }

  // kv base: kb[b][d] row-major, this thread's 4 b-rows are b_off+nf*16+l15
  const float* kvB = kb + (size_t)(b0 + b_off + l15) * ND;
  float kvc[4];
  #pragma unroll
  for (int nf = 0; nf < 4; ++nf) kvc[nf] = kvB[nf * 16 * ND + 0];

  f32x4 acc[4][4], fin[4][4];
  #pragma unroll
  for (int i = 0; i < 4; ++i)
    #pragma unroll
    for (int jj = 0; jj < 4; ++jj) { acc[i][jj] = (f32x4)0.0f; fin[i][jj] = (f32x4)0.0f; }

  // ---- main loop over d = 0..24 ----
  int p = 0;
  for (int n = 0; n < 25; ++n) {
    const int m = n + 2;
    if (m <= lastA) issueA(m, m % 3);   // in flight across the next barrier

    float kvn[4];
    if (n < 24) {
      #pragma unroll
      for (int nf = 0; nf < 4; ++nf) kvn[nf] = kvB[nf * 16 * ND + (n + 1)];
    } else {
      #pragma unroll
      for (int nf = 0; nf < 4; ++nf) kvn[nf] = 0.0f;
    }

    // 16 scaled MFMAs on buf p, chained into acc (no reset — telescoping)
    {
      i32x8 af[4];
      #pragma unroll
      for (int mf = 0; mf < 4; ++mf) {
        int rb = (o_off + mf * 16 + l15) * BKB;
        i32x4 lo = *reinterpret_cast<const i32x4*>(&Als[p][rb + s0]);
        i32x4 hi = *reinterpret_cast<const i32x4*>(&Als[p][rb + s1]);
        i32x8 v;
        v[0] = lo[0]; v[1] = lo[1]; v[2] = lo[2]; v[3] = lo[3];
        v[4] = hi[0]; v[5] = hi[1]; v[6] = hi[2]; v[7] = hi[3];
        af[mf] = v;
      }
      #pragma unroll
      for (int mf = 0; mf < 4; ++mf)
        #pragma unroll
        for (int nf = 0; nf < 4; ++nf)
          acc[mf][nf] = __builtin_amdgcn_mfma_scale_f32_16x16x128_f8f6f4(
              af[mf], bfr[nf], acc[mf][nf],
              0, 0, 0, 0x7f7f7f7f, 0, 0x7f7f7f7f);
    }

    // telescoping flush: fin += (kv_n - kv_{n+1}) * acc
    {
      float dk[4];
      #pragma unroll
      for (int nf = 0; nf < 4; ++nf) dk[nf] = kvc[nf] - kvn[nf];
      #pragma unroll
      for (int mf = 0; mf < 4; ++mf)
        #pragma unroll
        for (int nf = 0; nf < 4; ++nf)
          #pragma unroll
          for (int r = 0; r < 4; ++r)
            fin[mf][nf][r] += dk[nf] * acc[mf][nf][r];
      #pragma unroll
      for (int nf = 0; nf < 4; ++nf) kvc[nf] = kvn[nf];
    }

    // counted wait: A(n+1) guaranteed landed (only the 8 newest ops —
    // A(n+2) + kv prefetch — may remain in flight; vmcnt is FIFO).
    if (n < 23) {
      asm volatile("s_waitcnt vmcnt(8)" ::: "memory");
    } else {
      asm volatile("s_waitcnt vmcnt(0)" ::: "memory");
    }
    if (n < 24 || tail) __builtin_amdgcn_s_barrier();
    p = (p + 1 == 3) ? 0 : p + 1;
  }

  // ---- bias K-tail (iw==3): A-tile 25 in Als[25%3==1], B from BTls ----
  if (tail) {
    i32x8 af[4], bft[4];
    #pragma unroll
    for (int mf = 0; mf < 4; ++mf) {
      int rb = (o_off + mf * 16 + l15) * BKB;
      i32x4 lo = *reinterpret_cast<const i32x4*>(&Als[1][rb + s0]);
      i32x4 hi = *reinterpret_cast<const i32x4*>(&Als[1][rb + s1]);
      i32x8 v;
      v[0] = lo[0]; v[1] = lo[1]; v[2] = lo[2]; v[3] = lo[3];
      v[4] = hi[0]; v[5] = hi[1]; v[6] = hi[2]; v[7] = hi[3];
      af[mf] = v;
    }
    #pragma unroll
    for (int nf = 0; nf < 4; ++nf) {
      int rb = (b_off + nf * 16 + l15) * BKB;
      i32x4 lo = *reinterpret_cast<const i32x4*>(&BTls[rb + s0]);
      i32x4 hi = *reinterpret_cast<const i32x4*>(&BTls[rb + s1]);
      i32x8 v;
      v[0] = lo[0]; v[1] = lo[1]; v[2] = lo[2]; v[3] = lo[3];
      v[4] = hi[0]; v[5] = hi[1]; v[6] = hi[2]; v[7] = hi[3];
      bft[nf] = v;
    }
    #pragma unroll
    for (int mf = 0; mf < 4; ++mf)
      #pragma unroll
      for (int nf = 0; nf < 4; ++nf)
        fin[mf][nf] = __builtin_amdgcn_mfma_scale_f32_16x16x128_f8f6f4(
            af[mf], bft[nf], fin[mf][nf],
            0, 0, 0, 0x7f7f7f7f, 0, 0x7f7f7f7f);
  }

  // ---- store partial as bf16 ----
  unsigned short* Pz = Pb + (size_t)iw * NB * OUTD_;
  #pragma unroll
  for (int mf = 0; mf < 4; ++mf)
    #pragma unroll
    for (int nf = 0; nf < 4; ++nf) {
      int bg = b0 + b_off + nf * 16 + l15;
      int og = o0 + o_off + mf * 16 + quad * 4;
      u32x2 pk;
      pk[0] = pk_bf16(fin[mf][nf][0], fin[mf][nf][1]);
      pk[1] = pk_bf16(fin[mf][nf][2], fin[mf][nf][3]);
      *reinterpret_cast<u32x2*>(&Pz[(size_t)bg * OUTD_ + og]) = pk;
    }
}

// ---------------------------------------------------------------------------
// epilogue: out[b][2+o..2+o+3] = relu(P0+P1+P2+P3)  (bias in K-tail)
// ---------------------------------------------------------------------------
__global__ __launch_bounds__(256) void epilogue_kernel(
    const unsigned short* __restrict__ Pb, float* __restrict__ out)
{
  const int idx = (blockIdx.x * 256 + threadIdx.x) * 4;   // < 4096*512
  const int b = idx >> 9;
  const int o = idx & 511;
  const size_t ps = (size_t)NB * OUTD_;
  float s[4] = {0.0f, 0.0f, 0.0f, 0.0f};
  #pragma unroll
  for (int z = 0; z < NSPL; ++z) {
    u16x4 v = *reinterpret_cast<const u16x4*>(&Pb[z * ps + idx]);
    #pragma unroll
    for (int e = 0; e < 4; ++e) s[e] += bf2f(v[e]);
  }
  float* op = out + (size_t)b * XCOLS + 2 + o;   // 8B-aligned
  float2 lo, hi;
  lo.x = s[0] > 0.0f ? s[0] : 0.0f;
  lo.y = s[1] > 0.0f ? s[1] : 0.0f;
  hi.x = s[2] > 0.0f ? s[2] : 0.0f;
  hi.y = s[3] > 0.0f ? s[3] : 0.0f;
  *(float2*)op = lo;
  *(float2*)(op + 2) = hi;
}

// ---------------------------------------------------------------------------
extern "C" void kernel_launch(void* const* d_in, const int* in_sizes, int n_in,
                              void* d_out, int out_size, void* d_ws, size_t ws_size,
                              hipStream_t stream) {
  const float* x    = (const float*)d_in[0];   // 4096 x 514
  const float* W    = (const float*)d_in[1];   // 512 x 512 x 25
  const float* bias = (const float*)d_in[2];   // 512 x 25
  float* out = (float*)d_out;
  char* ws = (char*)d_ws;

  // ws layout (bytes):
  //   Xf8 2,097,152 | Wf8 512*12928 = 6,619,136 | kb 409,600
  //   kbT8 524,288 | Pb 4*4096*512*2 = 16,777,216   (total ~26.4 MB)
  const size_t xf_off  = 0;
  const size_t wf_off  = 2097152;
  const size_t kb_off  = wf_off + (size_t)OUTD_ * KT2B;
  const size_t kbt_off = kb_off + 409600;
  const size_t p_off   = kbt_off + (size_t)NB * 128;
  unsigned char* Xf8  = (unsigned char*)(ws + xf_off);
  unsigned char* Wf8  = (unsigned char*)(ws + wf_off);
  float* kb           = (float*)(ws + kb_off);
  unsigned char* kbT8 = (unsigned char*)(ws + kbt_off);
  unsigned short* Pb  = (unsigned short*)(ws + p_off);

  prep_all_kernel<<<1536, 256, 0, stream>>>(x, W, bias, Xf8, kb, kbT8, Wf8, out);
  gemm_mx_kernel<<<256, 512, 0, stream>>>(Wf8, Xf8, kb, kbT8, Pb);
  epilogue_kernel<<<(NB * OUTD_) / 1024, 256, 0, stream>>>(Pb, out);
}